// Round 7
// baseline (38028.085 us; speedup 1.0000x reference)
//
#include <hip/hip_runtime.h>
#include <cstdint>

// GRU persistent kernel v7: T=512, B=64, I=512, H=1024, O=512, fp32.
// 512 blocks = 128 j-tiles (8 cols) x 4 batch-quarters (16 b), 512 threads.
// TWO blocks/CU (LDS 74 KB): 16 waves/CU = 4/SIMD with the 128-VGPR budget
// that 512-thread blocks empirically get (v3). W_rh/W_hh j-slices (64 KB) in
// swizzled LDS; W_zh STREAMED from L2 in phase A2 (latency hidden under
// barrier A); x-gate weights pre-transposed [j][k] streamed in C; W_out raw.
// 4 independent barrier groups (one per b-quarter), relaxed spin + one
// acquire fence. Phases per step:
//   A : r = sigmoid(h@W_rh + xr_pre + b_r); s = r*h        -> arrive(A)
//   A2: z = sigmoid(h@W_zh + xz_pre + b_z); y_{t-1}=h@Wout -> wait(A)
//   B : ht = tanh(s@W_hh + xh_pre + b_h); h += z*(ht-h)    -> arrive(B)
//   C : xr/xz/xh_pre for step t+1 (x only, hides barrier B) -> wait(B)

#define TT 512
#define BB 64
#define II 512
#define HH 1024
#define OO 512
#define NTHR 512
#define NBLK 512

typedef float4 f4;
__device__ __forceinline__ f4 ld4(const float* p){ return *reinterpret_cast<const f4*>(p); }
// weight reads: per-wave k offsets {0,8,...,120}. XOR float-idx bits[3:2]
// with k bits[6:5]: the 16 b128 reads land 2-per-bank-quad (perfect 2-way,
// ~free). f4 alignment preserved (bits 1:0 untouched).
__device__ __forceinline__ int swz(int k){ return k ^ (((k >> 5) & 3) << 2); }

// ---------------- one-time prep kernels ----------------
__global__ void k_transpose_x(const float* __restrict__ x, float* __restrict__ xT){
  // x[t][b][i] -> xT[t][i][b]
  size_t total = (size_t)TT * II * BB;
  for (size_t n = (size_t)blockIdx.x * blockDim.x + threadIdx.x; n < total;
       n += (size_t)gridDim.x * blockDim.x){
    size_t t = n / ((size_t)II * BB);
    size_t rem = n % ((size_t)II * BB);
    size_t i = rem / BB, b = rem % BB;
    xT[n] = x[(t * BB + b) * II + i];
  }
}

__global__ void k_transpose_wx(const float* __restrict__ W, float* __restrict__ WT){
  // W[k][j] (I x H) -> WT[j][k] (H x I)
  size_t n = (size_t)blockIdx.x * blockDim.x + threadIdx.x;
  if (n >= (size_t)II * HH) return;
  size_t j = n / II, k = n % II;
  WT[n] = W[k * HH + j];
}

__global__ void k_transpose_h0(const float* __restrict__ st, float* __restrict__ h0){
  // state[b][j] -> h0[j][b]
  size_t n = (size_t)blockIdx.x * blockDim.x + threadIdx.x;
  if (n >= (size_t)HH * BB) return;
  size_t j = n / BB, b = n % BB;
  h0[n] = st[b * HH + j];
}

__global__ void k_init_bars(unsigned* bars){
  if (threadIdx.x < 1024) bars[threadIdx.x] = 0;
}

// ------------- barrier: 4 groups x 128 blocks, 8 leaves x 16 arrivals -------------
__device__ __forceinline__ void g_arrive(unsigned* bars, int g, int jt, unsigned ep){
  __builtin_amdgcn_fence(__ATOMIC_RELEASE, "agent");
  unsigned* leaf = bars + (g * 9 + (jt & 7)) * 16;
  unsigned old = __hip_atomic_fetch_add(leaf, 1u, __ATOMIC_RELAXED, __HIP_MEMORY_SCOPE_AGENT);
  if (old + 1u == ep * 16u)
    __hip_atomic_fetch_add(bars + (g * 9 + 8) * 16, 1u, __ATOMIC_RELAXED, __HIP_MEMORY_SCOPE_AGENT);
}
__device__ __forceinline__ void g_wait(unsigned* bars, int g, unsigned ep){
  unsigned* root = bars + (g * 9 + 8) * 16;
  while (__hip_atomic_load(root, __ATOMIC_RELAXED, __HIP_MEMORY_SCOPE_AGENT) < ep * 8u)
    __builtin_amdgcn_s_sleep(1);
  __builtin_amdgcn_fence(__ATOMIC_ACQUIRE, "agent");
}

// reduce over the 4 in-wave ksec bits (tid bits [5:2] -> lane xor 4,8,16,32)
#define WREDUCE(v) { v += __shfl_xor(v, 4); v += __shfl_xor(v, 8); \
                     v += __shfl_xor(v, 16); v += __shfl_xor(v, 32); }

// ---------------- the persistent GRU kernel ----------------
__global__ __launch_bounds__(NTHR, 2) void k_gru(
    const float* __restrict__ xT,
    const float* __restrict__ WxTr, const float* __restrict__ WxTz, const float* __restrict__ WxTh,
    float* __restrict__ h, float* __restrict__ s,
    const float* __restrict__ W_zh, const float* __restrict__ b_z,
    const float* __restrict__ W_rh, const float* __restrict__ b_r,
    const float* __restrict__ W_hh, const float* __restrict__ b_h,
    const float* __restrict__ W_out, const float* __restrict__ b_out,
    float* __restrict__ out, unsigned* __restrict__ bars)
{
  __shared__ float sW[2 * 8 * 1024];   // [0=RH,1=HH][c<8][k swz]  64 KB
  __shared__ float red[8 * 256];       // cross-wave reduce         8 KB
  __shared__ float xpre[3][128];       // x-projections (8c x 16b)
  __shared__ float sZ[128];            // z gate
  __shared__ float sBias[32];          // b_r[8] b_z[8] b_h[8] b_out[4]

  const int tid = threadIdx.x;
  const int bid = blockIdx.x;
  const int jt = bid & 127, bq = bid >> 7;
  const int j0 = jt * 8, o0 = jt * 4, bbase = bq * 16;

  // ---- prologue: W_rh / W_hh slices -> swizzled LDS ----
  #pragma unroll
  for (int kk2 = 0; kk2 < 2; ++kk2){
    const int k = tid * 2 + kk2;           // 0..1023
    f4 vr  = ld4(W_rh + (size_t)k * HH + j0);
    f4 vr2 = ld4(W_rh + (size_t)k * HH + j0 + 4);
    f4 vh  = ld4(W_hh + (size_t)k * HH + j0);
    f4 vh2 = ld4(W_hh + (size_t)k * HH + j0 + 4);
    const int kx = swz(k);
    float ar[8] = {vr.x,vr.y,vr.z,vr.w,vr2.x,vr2.y,vr2.z,vr2.w};
    float ah[8] = {vh.x,vh.y,vh.z,vh.w,vh2.x,vh2.y,vh2.z,vh2.w};
    #pragma unroll
    for (int c = 0; c < 8; ++c){
      sW[0*8192 + c*1024 + kx] = ar[c];
      sW[1*8192 + c*1024 + kx] = ah[c];
    }
  }
  if (tid < 8){
    sBias[tid]      = b_r[j0 + tid];
    sBias[8 + tid]  = b_z[j0 + tid];
    sBias[16 + tid] = b_h[j0 + tid];
    if (tid < 4) sBias[24 + tid] = b_out[o0 + tid];
  }

  const int bg = tid & 3, b0 = bbase + bg * 4;
  const int ksec = tid >> 2;           // 0..127
  const int wv = tid >> 6;             // wave 0..7
  const bool wr0 = ((tid & 60) == 0);  // (ksec & 15) == 0
  const int kh0 = ksec * 8;            // K=1024 / 128
  const int kx0 = ksec * 4;            // K=512  / 128
  __syncthreads();

  for (int t = -1; t < TT; ++t){
    f4 st4[8];                         // h stash, A -> A2
    if (t >= 0){
      // ================= A: r gate =================
      float aR[8][4] = {};
      const float* hb = h + kh0 * BB + b0;
      #pragma unroll
      for (int i4 = 0; i4 < 2; ++i4){
        #pragma unroll
        for (int kk = 0; kk < 4; ++kk) st4[i4*4+kk] = ld4(hb + (i4*4+kk) * BB);
        const int kxc = swz(kh0 + i4*4);
        #pragma unroll
        for (int c = 0; c < 8; ++c){
          f4 wf = *reinterpret_cast<const f4*>(&sW[0*8192 + c*1024 + kxc]);
          float wvv[4] = {wf.x, wf.y, wf.z, wf.w};
          #pragma unroll
          for (int kk = 0; kk < 4; ++kk){
            const f4 hv = st4[i4*4+kk];
            aR[c][0] = fmaf(wvv[kk], hv.x, aR[c][0]);
            aR[c][1] = fmaf(wvv[kk], hv.y, aR[c][1]);
            aR[c][2] = fmaf(wvv[kk], hv.z, aR[c][2]);
            aR[c][3] = fmaf(wvv[kk], hv.w, aR[c][3]);
          }
        }
      }
      #pragma unroll
      for (int c = 0; c < 8; ++c)
        #pragma unroll
        for (int bb = 0; bb < 4; ++bb) WREDUCE(aR[c][bb]);
      if (wr0)
        #pragma unroll
        for (int c = 0; c < 8; ++c)
          #pragma unroll
          for (int bb = 0; bb < 4; ++bb)
            red[wv*256 + c*16 + bg*4 + bb] = aR[c][bb];
      __syncthreads();
      if (tid < 128){
        float sum = 0.f;
        #pragma unroll
        for (int w = 0; w < 8; ++w) sum += red[w*256 + tid];
        const int c = tid >> 4, bl = tid & 15;
        const float v = sum + xpre[0][tid] + sBias[c];
        const float rr = 1.f / (1.f + expf(-v));
        const int jg = j0 + c, bgl = bbase + bl;
        s[jg*BB + bgl] = rr * h[jg*BB + bgl];
      }
      __syncthreads();
      if (tid == 0) g_arrive(bars, bq, jt, 2*t + 1);

      // ======= A2: z gate (W_zh streamed from L2) + y_{t-1} (hides barrier A) =======
      float aZ[8][4] = {};
      float aY[4][4] = {};
      #pragma unroll
      for (int i4 = 0; i4 < 2; ++i4){
        #pragma unroll
        for (int kk = 0; kk < 4; ++kk){
          const int k = kh0 + i4*4 + kk;
          f4 wz0 = ld4(W_zh + (size_t)k * HH + j0);
          f4 wz1 = ld4(W_zh + (size_t)k * HH + j0 + 4);
          const f4 hv = st4[i4*4+kk];
          float wza[8] = {wz0.x,wz0.y,wz0.z,wz0.w,wz1.x,wz1.y,wz1.z,wz1.w};
          #pragma unroll
          for (int c = 0; c < 8; ++c){
            aZ[c][0] = fmaf(wza[c], hv.x, aZ[c][0]);
            aZ[c][1] = fmaf(wza[c], hv.y, aZ[c][1]);
            aZ[c][2] = fmaf(wza[c], hv.z, aZ[c][2]);
            aZ[c][3] = fmaf(wza[c], hv.w, aZ[c][3]);
          }
        }
        const int kc = kh0 + i4*4;
        #pragma unroll
        for (int oc = 0; oc < 4; ++oc){
          f4 wo = ld4(W_out + (size_t)(o0 + oc) * HH + kc);
          float wvv[4] = {wo.x, wo.y, wo.z, wo.w};
          #pragma unroll
          for (int kk = 0; kk < 4; ++kk){
            const f4 hv = st4[i4*4+kk];
            aY[oc][0] = fmaf(wvv[kk], hv.x, aY[oc][0]);
            aY[oc][1] = fmaf(wvv[kk], hv.y, aY[oc][1]);
            aY[oc][2] = fmaf(wvv[kk], hv.z, aY[oc][2]);
            aY[oc][3] = fmaf(wvv[kk], hv.w, aY[oc][3]);
          }
        }
      }
      #pragma unroll
      for (int c = 0; c < 8; ++c)
        #pragma unroll
        for (int bb = 0; bb < 4; ++bb) WREDUCE(aZ[c][bb]);
      #pragma unroll
      for (int oc = 0; oc < 4; ++oc)
        #pragma unroll
        for (int bb = 0; bb < 4; ++bb) WREDUCE(aY[oc][bb]);
      if (wr0){
        #pragma unroll
        for (int c = 0; c < 8; ++c)
          #pragma unroll
          for (int bb = 0; bb < 4; ++bb)
            red[wv*256 + c*16 + bg*4 + bb] = aZ[c][bb];
        #pragma unroll
        for (int oc = 0; oc < 4; ++oc)
          #pragma unroll
          for (int bb = 0; bb < 4; ++bb)
            red[wv*256 + 128 + oc*16 + bg*4 + bb] = aY[oc][bb];
      }
      __syncthreads();
      if (tid < 128){
        float sum = 0.f;
        #pragma unroll
        for (int w = 0; w < 8; ++w) sum += red[w*256 + tid];
        const int c = tid >> 4;
        sZ[tid] = 1.f / (1.f + expf(-(sum + xpre[1][tid] + sBias[8 + c])));
      } else if (tid < 192){
        const int idx = tid - 128;
        float sum = 0.f;
        #pragma unroll
        for (int w = 0; w < 8; ++w) sum += red[w*256 + tid];
        const int oc = idx >> 4, bl = idx & 15;
        if (t > 0)
          out[((size_t)(t-1)*BB + bbase + bl)*OO + o0 + oc] = sum + sBias[24 + oc];
      }
      if (tid == 0) g_wait(bars, bq, 2*t + 1);
      __syncthreads();

      // ================= B: candidate + h update =================
      float aH[8][4] = {};
      const float* sb = s + kh0 * BB + b0;
      #pragma unroll
      for (int i4 = 0; i4 < 2; ++i4){
        f4 sv4[4];
        #pragma unroll
        for (int kk = 0; kk < 4; ++kk) sv4[kk] = ld4(sb + (i4*4+kk) * BB);
        const int kxc = swz(kh0 + i4*4);
        #pragma unroll
        for (int c = 0; c < 8; ++c){
          f4 wf = *reinterpret_cast<const f4*>(&sW[1*8192 + c*1024 + kxc]);
          float wvv[4] = {wf.x, wf.y, wf.z, wf.w};
          #pragma unroll
          for (int kk = 0; kk < 4; ++kk){
            aH[c][0] = fmaf(wvv[kk], sv4[kk].x, aH[c][0]);
            aH[c][1] = fmaf(wvv[kk], sv4[kk].y, aH[c][1]);
            aH[c][2] = fmaf(wvv[kk], sv4[kk].z, aH[c][2]);
            aH[c][3] = fmaf(wvv[kk], sv4[kk].w, aH[c][3]);
          }
        }
      }
      #pragma unroll
      for (int c = 0; c < 8; ++c)
        #pragma unroll
        for (int bb = 0; bb < 4; ++bb) WREDUCE(aH[c][bb]);
      if (wr0)
        #pragma unroll
        for (int c = 0; c < 8; ++c)
          #pragma unroll
          for (int bb = 0; bb < 4; ++bb)
            red[wv*256 + c*16 + bg*4 + bb] = aH[c][bb];
      __syncthreads();
      if (tid < 128){
        float sum = 0.f;
        #pragma unroll
        for (int w = 0; w < 8; ++w) sum += red[w*256 + tid];
        const int c = tid >> 4, bl = tid & 15;
        const int jg = j0 + c, bgl = bbase + bl;
        const float ht = tanhf(sum + xpre[2][tid] + sBias[16 + c]);
        const float z = sZ[tid];
        const float hold = h[jg*BB + bgl];
        const float hnew = fmaf(z, ht - hold, hold);
        h[jg*BB + bgl] = hnew;
        if (t == TT - 1) out[(size_t)TT*BB*OO + (size_t)bgl*HH + jg] = hnew;
      }
      __syncthreads();
      if (tid == 0) g_arrive(bars, bq, jt, 2*t + 2);
    }

    // ============ C: x-projections for step t+1 (hides barrier B) ============
    if (t + 1 < TT){
      const int tc = t + 1;
      const float* xb = xT + (size_t)tc * II * BB + kx0 * BB + b0;
      f4 xv4[4];
      #pragma unroll
      for (int kk = 0; kk < 4; ++kk) xv4[kk] = ld4(xb + kk * BB);

      // pass 1: r & z projections
      {
        float aXr[8][4] = {}, aXz[8][4] = {};
        #pragma unroll
        for (int c = 0; c < 8; ++c){
          f4 wr_ = ld4(WxTr + (size_t)(j0 + c) * II + kx0);
          f4 wz_ = ld4(WxTz + (size_t)(j0 + c) * II + kx0);
          float wrv[4] = {wr_.x, wr_.y, wr_.z, wr_.w};
          float wzv[4] = {wz_.x, wz_.y, wz_.z, wz_.w};
          #pragma unroll
          for (int kk = 0; kk < 4; ++kk){
            const f4 xv = xv4[kk];
            aXr[c][0] = fmaf(wrv[kk], xv.x, aXr[c][0]);
            aXr[c][1] = fmaf(wrv[kk], xv.y, aXr[c][1]);
            aXr[c][2] = fmaf(wrv[kk], xv.z, aXr[c][2]);
            aXr[c][3] = fmaf(wrv[kk], xv.w, aXr[c][3]);
            aXz[c][0] = fmaf(wzv[kk], xv.x, aXz[c][0]);
            aXz[c][1] = fmaf(wzv[kk], xv.y, aXz[c][1]);
            aXz[c][2] = fmaf(wzv[kk], xv.z, aXz[c][2]);
            aXz[c][3] = fmaf(wzv[kk], xv.w, aXz[c][3]);
          }
        }
        #pragma unroll
        for (int c = 0; c < 8; ++c)
          #pragma unroll
          for (int bb = 0; bb < 4; ++bb){ WREDUCE(aXr[c][bb]); WREDUCE(aXz[c][bb]); }
        if (wr0)
          #pragma unroll
          for (int c = 0; c < 8; ++c)
            #pragma unroll
            for (int bb = 0; bb < 4; ++bb){
              red[wv*256 + c*16 + bg*4 + bb]       = aXr[c][bb];
              red[wv*256 + 128 + c*16 + bg*4 + bb] = aXz[c][bb];
            }
      }
      __syncthreads();
      if (tid < 256){
        float sum = 0.f;
        #pragma unroll
        for (int w = 0; w < 8; ++w) sum += red[w*256 + tid];
        if (tid < 128) xpre[0][tid] = sum;
        else           xpre[1][tid - 128] = sum;
      }
      __syncthreads();

      // pass 2: h projection
      {
        float aXh[8][4] = {};
        #pragma unroll
        for (int c = 0; c < 8; ++c){
          f4 wh_ = ld4(WxTh + (size_t)(j0 + c) * II + kx0);
          float whv[4] = {wh_.x, wh_.y, wh_.z, wh_.w};
          #pragma unroll
          for (int kk = 0; kk < 4; ++kk){
            const f4 xv = xv4[kk];
            aXh[c][0] = fmaf(whv[kk], xv.x, aXh[c][0]);
            aXh[c][1] = fmaf(whv[kk], xv.y, aXh[c][1]);
            aXh[c][2] = fmaf(whv[kk], xv.z, aXh[c][2]);
            aXh[c][3] = fmaf(whv[kk], xv.w, aXh[c][3]);
          }
        }
        #pragma unroll
        for (int c = 0; c < 8; ++c)
          #pragma unroll
          for (int bb = 0; bb < 4; ++bb) WREDUCE(aXh[c][bb]);
        if (wr0)
          #pragma unroll
          for (int c = 0; c < 8; ++c)
            #pragma unroll
            for (int bb = 0; bb < 4; ++bb)
              red[wv*256 + c*16 + bg*4 + bb] = aXh[c][bb];
      }
      __syncthreads();
      if (tid < 128){
        float sum = 0.f;
        #pragma unroll
        for (int w = 0; w < 8; ++w) sum += red[w*256 + tid];
        xpre[2][tid] = sum;
      }
      __syncthreads();
    }

    if (t >= 0){
      if (tid == 0) g_wait(bars, bq, 2*t + 2);
      __syncthreads();
    }
  }

  // ================= trailing y_{T-1} from final h =================
  {
    float aY[4][4] = {};
    const float* hb = h + kh0 * BB + b0;
    #pragma unroll
    for (int i4 = 0; i4 < 2; ++i4){
      f4 hv4[4];
      #pragma unroll
      for (int kk = 0; kk < 4; ++kk) hv4[kk] = ld4(hb + (i4*4+kk) * BB);
      const int kc = kh0 + i4*4;
      #pragma unroll
      for (int oc = 0; oc < 4; ++oc){
        f4 wo = ld4(W_out + (size_t)(o0 + oc) * HH + kc);
        float wvv[4] = {wo.x, wo.y, wo.z, wo.w};
        #pragma unroll
        for (int kk = 0; kk < 4; ++kk){
          aY[oc][0] = fmaf(wvv[kk], hv4[kk].x, aY[oc][0]);
          aY[oc][1] = fmaf(wvv[kk], hv4[kk].y, aY[oc][1]);
          aY[oc][2] = fmaf(wvv[kk], hv4[kk].z, aY[oc][2]);
          aY[oc][3] = fmaf(wvv[kk], hv4[kk].w, aY[oc][3]);
        }
      }
    }
    #pragma unroll
    for (int oc = 0; oc < 4; ++oc)
      #pragma unroll
      for (int bb = 0; bb < 4; ++bb) WREDUCE(aY[oc][bb]);
    if (wr0)
      #pragma unroll
      for (int oc = 0; oc < 4; ++oc)
        #pragma unroll
        for (int bb = 0; bb < 4; ++bb)
          red[wv*256 + oc*16 + bg*4 + bb] = aY[oc][bb];
    __syncthreads();
    if (tid < 64){
      float sum = 0.f;
      #pragma unroll
      for (int w = 0; w < 8; ++w) sum += red[w*256 + tid];
      const int oc = tid >> 4, bl = tid & 15;
      out[((size_t)(TT-1)*BB + bbase + bl)*OO + o0 + oc] = sum + sBias[24 + oc];
    }
  }
}

// ---------------- host ----------------
extern "C" void kernel_launch(void* const* d_in, const int* in_sizes, int n_in,
                              void* d_out, int out_size, void* d_ws, size_t ws_size,
                              hipStream_t stream) {
  const float* x     = (const float*)d_in[0];
  const float* st    = (const float*)d_in[1];
  const float* W_zh  = (const float*)d_in[2];
  const float* W_zx  = (const float*)d_in[3];
  const float* b_z   = (const float*)d_in[4];
  const float* W_rh  = (const float*)d_in[5];
  const float* W_rx  = (const float*)d_in[6];
  const float* b_r   = (const float*)d_in[7];
  const float* W_hh  = (const float*)d_in[8];
  const float* W_hx  = (const float*)d_in[9];
  const float* b_h   = (const float*)d_in[10];
  const float* W_out = (const float*)d_in[11];
  const float* b_out = (const float*)d_in[12];
  float* out = (float*)d_out;
  float* ws  = (float*)d_ws;

  const size_t xT_sz = (size_t)TT * II * BB;   // 16,777,216
  const size_t wx_sz = (size_t)II * HH;        //    524,288
  const size_t h_sz  = (size_t)HH * BB;        //     65,536
  const size_t need  = (xT_sz + 3*wx_sz + 2*h_sz) * sizeof(float) + 1024*sizeof(unsigned);
  if (ws_size < need) return;

  float* xT   = ws;
  float* WxTr = xT + xT_sz;
  float* WxTz = WxTr + wx_sz;
  float* WxTh = WxTz + wx_sz;
  float* h    = WxTh + wx_sz;
  float* s    = h + h_sz;
  unsigned* bars = (unsigned*)(s + h_sz);

  k_transpose_x <<<8192, 256, 0, stream>>>(x, xT);
  k_transpose_wx<<<2048, 256, 0, stream>>>(W_rx, WxTr);
  k_transpose_wx<<<2048, 256, 0, stream>>>(W_zx, WxTz);
  k_transpose_wx<<<2048, 256, 0, stream>>>(W_hx, WxTh);
  k_transpose_h0<<< 256, 256, 0, stream>>>(st, h);
  k_init_bars   <<<   1, 1024, 0, stream>>>(bars);

  k_gru<<<NBLK, NTHR, 0, stream>>>(xT, WxTr, WxTz, WxTh, h, s,
                                   W_zh, b_z, W_rh, b_r, W_hh, b_h,
                                   W_out, b_out, out, bars);
}

// Round 8
// 25900.513 us; speedup vs baseline: 1.4682x; 1.4682x over previous
//
#include <hip/hip_runtime.h>
#include <cstdint>

// GRU persistent kernel v8: T=512, B=64, I=512, H=1024, O=512, fp32.
// v3 structure (256 blocks = 128 j-tiles x 2 batch-halves, 512 thr) with the
// LDS diet that enables TWO blocks/CU (v7 isolated co-residency to LDS:
// 2x74.5 KB refused; ~128 KB budget). Only W_rh stays in LDS (32 KB);
// W_zh is streamed from L2 in A2 (latency hidden under barrier A, pattern
// proven spill-free at 128 VGPR in v7); W_hh streamed in B. Total LDS 54 KB
// -> 2 blocks/CU = 16 waves/CU = 4/SIMD. Co-resident blocks belong to
// different barrier groups -> cross-block latency overlap.
// Phases per step:
//   A : r = sigmoid(h@W_rh + xr_pre + b_r); s = r*h        -> arrive(A)
//   A2: z = sigmoid(h@W_zh + xz_pre + b_z); y_{t-1}=h@Wout -> wait(A)
//   B : ht = tanh(s@W_hh + xh_pre + b_h); h += z*(ht-h)    -> arrive(B)
//   C : xr/xz/xh_pre for step t+1 (x only, hides barrier B) -> wait(B)

#define TT 512
#define BB 64
#define II 512
#define HH 1024
#define OO 512
#define NTHR 512

typedef float4 f4;
__device__ __forceinline__ f4 ld4(const float* p){ return *reinterpret_cast<const f4*>(p); }
// k-swizzle for ksec-stride-16 LDS weight reads (v3-verified: conflicts ~0)
__device__ __forceinline__ int swz(int k){ return k ^ (((k >> 4) & 7) << 2); }

// ---------------- one-time prep kernels ----------------
__global__ void k_transpose_x(const float* __restrict__ x, float* __restrict__ xT){
  // x[t][b][i] -> xT[t][i][b]
  size_t total = (size_t)TT * II * BB;
  for (size_t n = (size_t)blockIdx.x * blockDim.x + threadIdx.x; n < total;
       n += (size_t)gridDim.x * blockDim.x){
    size_t t = n / ((size_t)II * BB);
    size_t rem = n % ((size_t)II * BB);
    size_t i = rem / BB, b = rem % BB;
    xT[n] = x[(t * BB + b) * II + i];
  }
}

__global__ void k_transpose_wx(const float* __restrict__ W, float* __restrict__ WT){
  // W[k][j] (I x H) -> WT[j][k] (H x I)
  size_t n = (size_t)blockIdx.x * blockDim.x + threadIdx.x;
  if (n >= (size_t)II * HH) return;
  size_t j = n / II, k = n % II;
  WT[n] = W[k * HH + j];
}

__global__ void k_transpose_h0(const float* __restrict__ st, float* __restrict__ h0){
  // state[b][j] -> h0[j][b]
  size_t n = (size_t)blockIdx.x * blockDim.x + threadIdx.x;
  if (n >= (size_t)HH * BB) return;
  size_t j = n / BB, b = n % BB;
  h0[n] = st[b * HH + j];
}

__global__ void k_init_bars(unsigned* bars){
  if (threadIdx.x < 512) bars[threadIdx.x] = 0;
}

// ---------------- barrier (per batch-half group of 128 blocks) ----------------
__device__ __forceinline__ void g_arrive(unsigned* bars, int g, int jt, unsigned ep){
  __builtin_amdgcn_fence(__ATOMIC_RELEASE, "agent");
  unsigned* leaf = bars + (g * 9 + (jt & 7)) * 16;
  unsigned old = __hip_atomic_fetch_add(leaf, 1u, __ATOMIC_RELAXED, __HIP_MEMORY_SCOPE_AGENT);
  if (old + 1u == ep * 16u)
    __hip_atomic_fetch_add(bars + (g * 9 + 8) * 16, 1u, __ATOMIC_RELAXED, __HIP_MEMORY_SCOPE_AGENT);
}
__device__ __forceinline__ void g_wait(unsigned* bars, int g, unsigned ep){
  unsigned* root = bars + (g * 9 + 8) * 16;
  while (__hip_atomic_load(root, __ATOMIC_RELAXED, __HIP_MEMORY_SCOPE_AGENT) < ep * 8u)
    __builtin_amdgcn_s_sleep(1);
  __builtin_amdgcn_fence(__ATOMIC_ACQUIRE, "agent");
}

// shfl-reduce over the 3 ksec bits inside a wave (lanes 8,16,32)
#define WREDUCE(v) { v += __shfl_xor(v, 8); v += __shfl_xor(v, 16); v += __shfl_xor(v, 32); }

// ---------------- the persistent GRU kernel ----------------
__global__ __launch_bounds__(NTHR, 2) void k_gru(
    const float* __restrict__ xT,
    const float* __restrict__ WxTr, const float* __restrict__ WxTz, const float* __restrict__ WxTh,
    float* __restrict__ h, float* __restrict__ s,
    const float* __restrict__ W_zh, const float* __restrict__ b_z,
    const float* __restrict__ W_rh, const float* __restrict__ b_r,
    const float* __restrict__ W_hh, const float* __restrict__ b_h,
    const float* __restrict__ W_out, const float* __restrict__ b_out,
    float* __restrict__ out, unsigned* __restrict__ bars)
{
  __shared__ float sW[8 * 1024];       // W_rh slice [c<8][k swz]   32 KB
  __shared__ float red[8 * 528];       // cross-wave reduce         16.9 KB
  __shared__ float xpre[3][256];       // x-projections for current step
  __shared__ float sZ[256];            // z gate
  __shared__ float sBias[32];          // b_r[8] b_z[8] b_h[8] b_out[4]

  const int tid = threadIdx.x;
  const int bid = blockIdx.x;
  const int jt = bid & 127, bhalf = bid >> 7;
  const int j0 = jt * 8, o0 = jt * 4, bbase = bhalf * 32;

  // ---- prologue: W_rh slice -> swizzled LDS ----
  #pragma unroll
  for (int kk2 = 0; kk2 < 2; ++kk2){
    const int k = tid * 2 + kk2;           // 0..1023
    f4 vr  = ld4(W_rh + (size_t)k * HH + j0);
    f4 vr2 = ld4(W_rh + (size_t)k * HH + j0 + 4);
    const int kx = swz(k);
    float ar[8] = {vr.x,vr.y,vr.z,vr.w,vr2.x,vr2.y,vr2.z,vr2.w};
    #pragma unroll
    for (int c = 0; c < 8; ++c) sW[c*1024 + kx] = ar[c];
  }
  if (tid < 8){
    sBias[tid]      = b_r[j0 + tid];
    sBias[8 + tid]  = b_z[j0 + tid];
    sBias[16 + tid] = b_h[j0 + tid];
    if (tid < 4) sBias[24 + tid] = b_out[o0 + tid];
  }

  const int bg = tid & 7, b0 = bbase + bg * 4;
  const int ksec = tid >> 3;           // 0..63
  const int wv = tid >> 6;             // wave 0..7
  const bool wr0 = ((tid & 56) == 0);  // in-wave ksec bits == 0
  const int kh0 = ksec * 16;           // K=1024 / 64
  const int kx0 = ksec * 8;            // K=512  / 64
  __syncthreads();

  for (int t = -1; t < TT; ++t){
    f4 st4[16];                        // h stash, A -> A2
    if (t >= 0){
      // ================= A: r gate (weights from LDS) =================
      float aR[8][4] = {};
      const float* hb = h + kh0 * BB + b0;
      #pragma unroll
      for (int i4 = 0; i4 < 4; ++i4){
        #pragma unroll
        for (int kk = 0; kk < 4; ++kk) st4[i4*4+kk] = ld4(hb + (i4*4+kk) * BB);
        const int kxc = swz(kh0 + i4*4);
        #pragma unroll
        for (int c = 0; c < 8; ++c){
          f4 wf = *reinterpret_cast<const f4*>(&sW[c*1024 + kxc]);
          float wvv[4] = {wf.x, wf.y, wf.z, wf.w};
          #pragma unroll
          for (int kk = 0; kk < 4; ++kk){
            const f4 hv = st4[i4*4+kk];
            aR[c][0] = fmaf(wvv[kk], hv.x, aR[c][0]);
            aR[c][1] = fmaf(wvv[kk], hv.y, aR[c][1]);
            aR[c][2] = fmaf(wvv[kk], hv.z, aR[c][2]);
            aR[c][3] = fmaf(wvv[kk], hv.w, aR[c][3]);
          }
        }
      }
      #pragma unroll
      for (int c = 0; c < 8; ++c)
        #pragma unroll
        for (int bb = 0; bb < 4; ++bb) WREDUCE(aR[c][bb]);
      if (wr0)
        #pragma unroll
        for (int c = 0; c < 8; ++c)
          #pragma unroll
          for (int bb = 0; bb < 4; ++bb)
            red[wv*528 + c*32 + bg*4 + bb] = aR[c][bb];
      __syncthreads();
      if (tid < 256){
        float sum = 0.f;
        #pragma unroll
        for (int w = 0; w < 8; ++w) sum += red[w*528 + tid];
        const int c = tid >> 5, bl = tid & 31;
        const float v = sum + xpre[0][tid] + sBias[c];
        const float rr = 1.f / (1.f + expf(-v));
        const int jg = j0 + c, bgl = bbase + bl;
        s[jg*BB + bgl] = rr * h[jg*BB + bgl];
      }
      __syncthreads();
      if (tid == 0) g_arrive(bars, bhalf, jt, 2*t + 1);

      // ==== A2: z gate (W_zh STREAMED) + y_{t-1} (hides barrier A) ====
      float aZ[8][4] = {};
      float aY[4][4] = {};
      #pragma unroll
      for (int i4 = 0; i4 < 4; ++i4){
        const int kc = kh0 + i4*4;
        #pragma unroll
        for (int kk = 0; kk < 4; ++kk){
          const int k = kc + kk;
          const f4 hv = st4[i4*4+kk];
          f4 wz0 = ld4(W_zh + (size_t)k * HH + j0);
          {
            float wza[4] = {wz0.x, wz0.y, wz0.z, wz0.w};
            #pragma unroll
            for (int c = 0; c < 4; ++c){
              aZ[c][0] = fmaf(wza[c], hv.x, aZ[c][0]);
              aZ[c][1] = fmaf(wza[c], hv.y, aZ[c][1]);
              aZ[c][2] = fmaf(wza[c], hv.z, aZ[c][2]);
              aZ[c][3] = fmaf(wza[c], hv.w, aZ[c][3]);
            }
          }
          f4 wz1 = ld4(W_zh + (size_t)k * HH + j0 + 4);
          {
            float wza[4] = {wz1.x, wz1.y, wz1.z, wz1.w};
            #pragma unroll
            for (int c = 0; c < 4; ++c){
              aZ[4+c][0] = fmaf(wza[c], hv.x, aZ[4+c][0]);
              aZ[4+c][1] = fmaf(wza[c], hv.y, aZ[4+c][1]);
              aZ[4+c][2] = fmaf(wza[c], hv.z, aZ[4+c][2]);
              aZ[4+c][3] = fmaf(wza[c], hv.w, aZ[4+c][3]);
            }
          }
        }
        #pragma unroll
        for (int oc = 0; oc < 4; ++oc){
          f4 wo = ld4(W_out + (size_t)(o0 + oc) * HH + kc);
          float wvv[4] = {wo.x, wo.y, wo.z, wo.w};
          #pragma unroll
          for (int kk = 0; kk < 4; ++kk){
            const f4 hv = st4[i4*4+kk];
            aY[oc][0] = fmaf(wvv[kk], hv.x, aY[oc][0]);
            aY[oc][1] = fmaf(wvv[kk], hv.y, aY[oc][1]);
            aY[oc][2] = fmaf(wvv[kk], hv.z, aY[oc][2]);
            aY[oc][3] = fmaf(wvv[kk], hv.w, aY[oc][3]);
          }
        }
      }
      #pragma unroll
      for (int c = 0; c < 8; ++c)
        #pragma unroll
        for (int bb = 0; bb < 4; ++bb) WREDUCE(aZ[c][bb]);
      #pragma unroll
      for (int oc = 0; oc < 4; ++oc)
        #pragma unroll
        for (int bb = 0; bb < 4; ++bb) WREDUCE(aY[oc][bb]);
      if (wr0){
        #pragma unroll
        for (int c = 0; c < 8; ++c)
          #pragma unroll
          for (int bb = 0; bb < 4; ++bb)
            red[wv*528 + c*32 + bg*4 + bb] = aZ[c][bb];
        #pragma unroll
        for (int oc = 0; oc < 4; ++oc)
          #pragma unroll
          for (int bb = 0; bb < 4; ++bb)
            red[wv*528 + 256 + oc*32 + bg*4 + bb] = aY[oc][bb];
      }
      __syncthreads();
      if (tid < 256){
        float sum = 0.f;
        #pragma unroll
        for (int w = 0; w < 8; ++w) sum += red[w*528 + tid];
        const int c = tid >> 5;
        sZ[tid] = 1.f / (1.f + expf(-(sum + xpre[1][tid] + sBias[8 + c])));
      } else if (tid < 384){
        const int idx = tid - 256;
        float sum = 0.f;
        #pragma unroll
        for (int w = 0; w < 8; ++w) sum += red[w*528 + tid];
        const int oc = idx >> 5, bl = idx & 31;
        if (t > 0)
          out[((size_t)(t-1)*BB + bbase + bl)*OO + o0 + oc] = sum + sBias[24 + oc];
      }
      if (tid == 0) g_wait(bars, bhalf, 2*t + 1);
      __syncthreads();

      // ===== B: candidate (W_hh STREAMED) + h update =====
      float aH[8][4] = {};
      const float* sb = s + kh0 * BB + b0;
      #pragma unroll
      for (int i4 = 0; i4 < 4; ++i4){
        f4 sv4[4];
        #pragma unroll
        for (int kk = 0; kk < 4; ++kk) sv4[kk] = ld4(sb + (i4*4+kk) * BB);
        #pragma unroll
        for (int kk = 0; kk < 4; ++kk){
          const int k = kh0 + i4*4 + kk;
          const f4 sv = sv4[kk];
          f4 wh0 = ld4(W_hh + (size_t)k * HH + j0);
          {
            float wha[4] = {wh0.x, wh0.y, wh0.z, wh0.w};
            #pragma unroll
            for (int c = 0; c < 4; ++c){
              aH[c][0] = fmaf(wha[c], sv.x, aH[c][0]);
              aH[c][1] = fmaf(wha[c], sv.y, aH[c][1]);
              aH[c][2] = fmaf(wha[c], sv.z, aH[c][2]);
              aH[c][3] = fmaf(wha[c], sv.w, aH[c][3]);
            }
          }
          f4 wh1 = ld4(W_hh + (size_t)k * HH + j0 + 4);
          {
            float wha[4] = {wh1.x, wh1.y, wh1.z, wh1.w};
            #pragma unroll
            for (int c = 0; c < 4; ++c){
              aH[4+c][0] = fmaf(wha[c], sv.x, aH[4+c][0]);
              aH[4+c][1] = fmaf(wha[c], sv.y, aH[4+c][1]);
              aH[4+c][2] = fmaf(wha[c], sv.z, aH[4+c][2]);
              aH[4+c][3] = fmaf(wha[c], sv.w, aH[4+c][3]);
            }
          }
        }
      }
      #pragma unroll
      for (int c = 0; c < 8; ++c)
        #pragma unroll
        for (int bb = 0; bb < 4; ++bb) WREDUCE(aH[c][bb]);
      if (wr0)
        #pragma unroll
        for (int c = 0; c < 8; ++c)
          #pragma unroll
          for (int bb = 0; bb < 4; ++bb)
            red[wv*528 + c*32 + bg*4 + bb] = aH[c][bb];
      __syncthreads();
      if (tid < 256){
        float sum = 0.f;
        #pragma unroll
        for (int w = 0; w < 8; ++w) sum += red[w*528 + tid];
        const int c = tid >> 5, bl = tid & 31;
        const int jg = j0 + c, bgl = bbase + bl;
        const float ht = tanhf(sum + xpre[2][tid] + sBias[16 + c]);
        const float z = sZ[tid];
        const float hold = h[jg*BB + bgl];
        const float hnew = fmaf(z, ht - hold, hold);
        h[jg*BB + bgl] = hnew;
        if (t == TT - 1) out[(size_t)TT*BB*OO + (size_t)bgl*HH + jg] = hnew;
      }
      __syncthreads();
      if (tid == 0) g_arrive(bars, bhalf, jt, 2*t + 2);
    }

    // ============ C: x-projections for step t+1 (hides barrier B) ============
    if (t + 1 < TT){
      const int tc = t + 1;
      float aXr[8][4] = {}, aXz[8][4] = {}, aXh[8][4] = {};
      const float* xb = xT + (size_t)tc * II * BB + kx0 * BB + b0;
      #pragma unroll
      for (int i4 = 0; i4 < 2; ++i4){
        f4 xv4[4];
        #pragma unroll
        for (int kk = 0; kk < 4; ++kk) xv4[kk] = ld4(xb + (i4*4+kk) * BB);
        #pragma unroll
        for (int c = 0; c < 8; ++c){
          f4 wr_ = ld4(WxTr + (size_t)(j0 + c) * II + kx0 + i4*4);
          f4 wz_ = ld4(WxTz + (size_t)(j0 + c) * II + kx0 + i4*4);
          f4 wh_ = ld4(WxTh + (size_t)(j0 + c) * II + kx0 + i4*4);
          float wrv[4] = {wr_.x, wr_.y, wr_.z, wr_.w};
          float wzv[4] = {wz_.x, wz_.y, wz_.z, wz_.w};
          float whv[4] = {wh_.x, wh_.y, wh_.z, wh_.w};
          #pragma unroll
          for (int kk = 0; kk < 4; ++kk){
            const f4 xv = xv4[kk];
            aXr[c][0] = fmaf(wrv[kk], xv.x, aXr[c][0]);
            aXr[c][1] = fmaf(wrv[kk], xv.y, aXr[c][1]);
            aXr[c][2] = fmaf(wrv[kk], xv.z, aXr[c][2]);
            aXr[c][3] = fmaf(wrv[kk], xv.w, aXr[c][3]);
            aXz[c][0] = fmaf(wzv[kk], xv.x, aXz[c][0]);
            aXz[c][1] = fmaf(wzv[kk], xv.y, aXz[c][1]);
            aXz[c][2] = fmaf(wzv[kk], xv.z, aXz[c][2]);
            aXz[c][3] = fmaf(wzv[kk], xv.w, aXz[c][3]);
            aXh[c][0] = fmaf(whv[kk], xv.x, aXh[c][0]);
            aXh[c][1] = fmaf(whv[kk], xv.y, aXh[c][1]);
            aXh[c][2] = fmaf(whv[kk], xv.z, aXh[c][2]);
            aXh[c][3] = fmaf(whv[kk], xv.w, aXh[c][3]);
          }
        }
      }
      #pragma unroll
      for (int c = 0; c < 8; ++c)
        #pragma unroll
        for (int bb = 0; bb < 4; ++bb){ WREDUCE(aXr[c][bb]); WREDUCE(aXz[c][bb]); WREDUCE(aXh[c][bb]); }
      if (wr0)
        #pragma unroll
        for (int c = 0; c < 8; ++c)
          #pragma unroll
          for (int bb = 0; bb < 4; ++bb){
            red[wv*528 + c*32 + bg*4 + bb]       = aXr[c][bb];
            red[wv*528 + 256 + c*32 + bg*4 + bb] = aXz[c][bb];
          }
      __syncthreads();
      {
        float sum = 0.f;
        #pragma unroll
        for (int w = 0; w < 8; ++w) sum += red[w*528 + tid];
        if (tid < 256) xpre[0][tid] = sum;
        else           xpre[1][tid - 256] = sum;
      }
      __syncthreads();
      if (wr0)
        #pragma unroll
        for (int c = 0; c < 8; ++c)
          #pragma unroll
          for (int bb = 0; bb < 4; ++bb)
            red[wv*528 + c*32 + bg*4 + bb] = aXh[c][bb];
      __syncthreads();
      if (tid < 256){
        float sum = 0.f;
        #pragma unroll
        for (int w = 0; w < 8; ++w) sum += red[w*528 + tid];
        xpre[2][tid] = sum;
      }
      __syncthreads();
    }

    if (t >= 0){
      if (tid == 0) g_wait(bars, bhalf, 2*t + 2);
      __syncthreads();
    }
  }

  // ================= trailing y_{T-1} from final h =================
  {
    float aY[4][4] = {};
    const float* hb = h + kh0 * BB + b0;
    #pragma unroll
    for (int i4 = 0; i4 < 4; ++i4){
      f4 hv4[4];
      #pragma unroll
      for (int kk = 0; kk < 4; ++kk) hv4[kk] = ld4(hb + (i4*4+kk) * BB);
      const int kc = kh0 + i4*4;
      #pragma unroll
      for (int oc = 0; oc < 4; ++oc){
        f4 wo = ld4(W_out + (size_t)(o0 + oc) * HH + kc);
        float wvv[4] = {wo.x, wo.y, wo.z, wo.w};
        #pragma unroll
        for (int kk = 0; kk < 4; ++kk){
          aY[oc][0] = fmaf(wvv[kk], hv4[kk].x, aY[oc][0]);
          aY[oc][1] = fmaf(wvv[kk], hv4[kk].y, aY[oc][1]);
          aY[oc][2] = fmaf(wvv[kk], hv4[kk].z, aY[oc][2]);
          aY[oc][3] = fmaf(wvv[kk], hv4[kk].w, aY[oc][3]);
        }
      }
    }
    #pragma unroll
    for (int oc = 0; oc < 4; ++oc)
      #pragma unroll
      for (int bb = 0; bb < 4; ++bb) WREDUCE(aY[oc][bb]);
    if (wr0)
      #pragma unroll
      for (int oc = 0; oc < 4; ++oc)
        #pragma unroll
        for (int bb = 0; bb < 4; ++bb)
          red[wv*528 + oc*32 + bg*4 + bb] = aY[oc][bb];
    __syncthreads();
    if (tid < 128){
      float sum = 0.f;
      #pragma unroll
      for (int w = 0; w < 8; ++w) sum += red[w*528 + tid];
      const int oc = tid >> 5, bl = tid & 31;
      out[((size_t)(TT-1)*BB + bbase + bl)*OO + o0 + oc] = sum + sBias[24 + oc];
    }
  }
}

// ---------------- host ----------------
extern "C" void kernel_launch(void* const* d_in, const int* in_sizes, int n_in,
                              void* d_out, int out_size, void* d_ws, size_t ws_size,
                              hipStream_t stream) {
  const float* x     = (const float*)d_in[0];
  const float* st    = (const float*)d_in[1];
  const float* W_zh  = (const float*)d_in[2];
  const float* W_zx  = (const float*)d_in[3];
  const float* b_z   = (const float*)d_in[4];
  const float* W_rh  = (const float*)d_in[5];
  const float* W_rx  = (const float*)d_in[6];
  const float* b_r   = (const float*)d_in[7];
  const float* W_hh  = (const float*)d_in[8];
  const float* W_hx  = (const float*)d_in[9];
  const float* b_h   = (const float*)d_in[10];
  const float* W_out = (const float*)d_in[11];
  const float* b_out = (const float*)d_in[12];
  float* out = (float*)d_out;
  float* ws  = (float*)d_ws;

  const size_t xT_sz = (size_t)TT * II * BB;   // 16,777,216
  const size_t wx_sz = (size_t)II * HH;        //    524,288
  const size_t h_sz  = (size_t)HH * BB;        //     65,536
  const size_t need  = (xT_sz + 3*wx_sz + 2*h_sz) * sizeof(float) + 512*sizeof(unsigned);
  if (ws_size < need) return;

  float* xT   = ws;
  float* WxTr = xT + xT_sz;
  float* WxTz = WxTr + wx_sz;
  float* WxTh = WxTz + wx_sz;
  float* h    = WxTh + wx_sz;
  float* s    = h + h_sz;
  unsigned* bars = (unsigned*)(s + h_sz);

  k_transpose_x <<<8192, 256, 0, stream>>>(x, xT);
  k_transpose_wx<<<2048, 256, 0, stream>>>(W_rx, WxTr);
  k_transpose_wx<<<2048, 256, 0, stream>>>(W_zx, WxTz);
  k_transpose_wx<<<2048, 256, 0, stream>>>(W_hx, WxTh);
  k_transpose_h0<<< 256, 256, 0, stream>>>(st, h);
  k_init_bars   <<<   1, 512, 0, stream>>>(bars);

  k_gru<<<256, NTHR, 0, stream>>>(xT, WxTr, WxTz, WxTh, h, s,
                                  W_zh, b_z, W_rh, b_r, W_hh, b_h,
                                  W_out, b_out, out, bars);
}

// Round 9
// 12977.904 us; speedup vs baseline: 2.9302x; 1.9957x over previous
//
#include <hip/hip_runtime.h>
#include <cstdint>

// GRU persistent kernel v9: T=512, B=64, I=512, H=1024, O=512, fp32.
// v3 structure (256 blocks = 128 j-tiles x 2 b-halves, 512 thr, all h-gate
// weights in 96 KB swizzled LDS) + FENCE-FREE coherent exchange:
//  - h and s are accessed ONLY via sc0+sc1 (L2-bypass, L3-coherent) inline-asm
//    loads/stores, batched 16x dwordx4 with a single vmcnt(0).
//  - grid barrier uses RELAXED atomics only; release ordering is provided by
//    the per-wave s_waitcnt vmcnt(0) that __syncthreads emits before s_barrier
//    (all waves drain their sc1 stores to L3 before tid0 arrives).
//  - NO acquire/release fences -> no buffer_inv -> x, W_out, xpre, weights
//    stay L2-resident for the whole scan (v8 showed the invalidate storm:
//    23 GB FETCH from streamed weights).
// Phases per step:
//   A : r = sigmoid(h@W_rh + xr_pre + b_r); s = r*h        -> arrive(A)
//   A2: z = sigmoid(h@W_zh + xz_pre + b_z); y_{t-1}=h@Wout -> wait(A)
//   B : ht = tanh(s@W_hh + xh_pre + b_h); h += z*(ht-h)    -> arrive(B)
//   C : xr/xz/xh_pre for step t+1 (x only, hides barrier B) -> wait(B)

#define TT 512
#define BB 64
#define II 512
#define HH 1024
#define OO 512
#define NTHR 512

typedef float4 f4;
__device__ __forceinline__ f4 ld4(const float* p){ return *reinterpret_cast<const f4*>(p); }
// k-swizzle for ksec-stride-16 LDS weight reads (v3-verified: conflicts ~0)
__device__ __forceinline__ int swz(int k){ return k ^ (((k >> 4) & 7) << 2); }

// ---- coherent (L2-bypass, L3-served) access helpers for h/s ----
// 16 consecutive-k f4 loads from one base (stride BB*4 = 256 B), 1 vmcnt.
__device__ __forceinline__ void ldc16(const float* p, f4* d){
  asm volatile(
    "global_load_dwordx4 %0,  %16, off sc0 sc1\n\t"
    "global_load_dwordx4 %1,  %16, off offset:256 sc0 sc1\n\t"
    "global_load_dwordx4 %2,  %16, off offset:512 sc0 sc1\n\t"
    "global_load_dwordx4 %3,  %16, off offset:768 sc0 sc1\n\t"
    "global_load_dwordx4 %4,  %16, off offset:1024 sc0 sc1\n\t"
    "global_load_dwordx4 %5,  %16, off offset:1280 sc0 sc1\n\t"
    "global_load_dwordx4 %6,  %16, off offset:1536 sc0 sc1\n\t"
    "global_load_dwordx4 %7,  %16, off offset:1792 sc0 sc1\n\t"
    "global_load_dwordx4 %8,  %16, off offset:2048 sc0 sc1\n\t"
    "global_load_dwordx4 %9,  %16, off offset:2304 sc0 sc1\n\t"
    "global_load_dwordx4 %10, %16, off offset:2560 sc0 sc1\n\t"
    "global_load_dwordx4 %11, %16, off offset:2816 sc0 sc1\n\t"
    "global_load_dwordx4 %12, %16, off offset:3072 sc0 sc1\n\t"
    "global_load_dwordx4 %13, %16, off offset:3328 sc0 sc1\n\t"
    "global_load_dwordx4 %14, %16, off offset:3584 sc0 sc1\n\t"
    "s_waitcnt vmcnt(1)\n\t"
    "global_load_dwordx4 %15, %16, off offset:3840 sc0 sc1\n\t"
    "s_waitcnt vmcnt(0)"
    : "=&v"(d[0]),"=&v"(d[1]),"=&v"(d[2]),"=&v"(d[3]),
      "=&v"(d[4]),"=&v"(d[5]),"=&v"(d[6]),"=&v"(d[7]),
      "=&v"(d[8]),"=&v"(d[9]),"=&v"(d[10]),"=&v"(d[11]),
      "=&v"(d[12]),"=&v"(d[13]),"=&v"(d[14]),"=&v"(d[15])
    : "v"(p) : "memory");
}
__device__ __forceinline__ float ldc1(const float* p){
  float v;
  asm volatile("global_load_dword %0, %1, off sc0 sc1\n\ts_waitcnt vmcnt(0)"
               : "=v"(v) : "v"(p) : "memory");
  return v;
}
__device__ __forceinline__ void stc1(float* p, float v){
  asm volatile("global_store_dword %0, %1, off sc0 sc1" :: "v"(p), "v"(v) : "memory");
}

// ---------------- one-time prep kernels ----------------
__global__ void k_transpose_x(const float* __restrict__ x, float* __restrict__ xT){
  size_t total = (size_t)TT * II * BB;
  for (size_t n = (size_t)blockIdx.x * blockDim.x + threadIdx.x; n < total;
       n += (size_t)gridDim.x * blockDim.x){
    size_t t = n / ((size_t)II * BB);
    size_t rem = n % ((size_t)II * BB);
    size_t i = rem / BB, b = rem % BB;
    xT[n] = x[(t * BB + b) * II + i];
  }
}

__global__ void k_transpose_wx(const float* __restrict__ W, float* __restrict__ WT){
  size_t n = (size_t)blockIdx.x * blockDim.x + threadIdx.x;
  if (n >= (size_t)II * HH) return;
  size_t j = n / II, k = n % II;
  WT[n] = W[k * HH + j];
}

__global__ void k_transpose_h0(const float* __restrict__ st, float* __restrict__ h0){
  size_t n = (size_t)blockIdx.x * blockDim.x + threadIdx.x;
  if (n >= (size_t)HH * BB) return;
  size_t j = n / BB, b = n % BB;
  h0[n] = st[b * HH + j];
}

__global__ void k_init_bars(unsigned* bars){
  if (threadIdx.x < 512) bars[threadIdx.x] = 0;
}

// ------- barrier: per b-half group of 128 blocks; RELAXED atomics only -------
// Correctness: every wave's sc1 data stores are drained to L3 by the
// s_waitcnt vmcnt(0) __syncthreads emits; tid0's leaf add happens after.
__device__ __forceinline__ void g_arrive(unsigned* bars, int g, int jt, unsigned ep){
  asm volatile("s_waitcnt vmcnt(0)" ::: "memory");
  unsigned* leaf = bars + (g * 9 + (jt & 7)) * 16;
  unsigned old = __hip_atomic_fetch_add(leaf, 1u, __ATOMIC_RELAXED, __HIP_MEMORY_SCOPE_AGENT);
  if (old + 1u == ep * 16u)
    __hip_atomic_fetch_add(bars + (g * 9 + 8) * 16, 1u, __ATOMIC_RELAXED, __HIP_MEMORY_SCOPE_AGENT);
}
__device__ __forceinline__ void g_wait(unsigned* bars, int g, unsigned ep){
  unsigned* root = bars + (g * 9 + 8) * 16;
  while (__hip_atomic_load(root, __ATOMIC_RELAXED, __HIP_MEMORY_SCOPE_AGENT) < ep * 8u)
    __builtin_amdgcn_s_sleep(1);
}

// shfl-reduce over the 3 ksec bits inside a wave (lanes 8,16,32)
#define WREDUCE(v) { v += __shfl_xor(v, 8); v += __shfl_xor(v, 16); v += __shfl_xor(v, 32); }

// ---------------- the persistent GRU kernel ----------------
__global__ __launch_bounds__(NTHR, 2) void k_gru(
    const float* __restrict__ xT,
    const float* __restrict__ WxTr, const float* __restrict__ WxTz, const float* __restrict__ WxTh,
    float* __restrict__ h, float* __restrict__ s,
    const float* __restrict__ W_zh, const float* __restrict__ b_z,
    const float* __restrict__ W_rh, const float* __restrict__ b_r,
    const float* __restrict__ W_hh, const float* __restrict__ b_h,
    const float* __restrict__ W_out, const float* __restrict__ b_out,
    float* __restrict__ out, unsigned* __restrict__ bars)
{
  __shared__ float sW[3 * 8 * 1024];   // [0=RH,1=ZH,2=HH][c<8][k swz]  96 KB
  __shared__ float red[8 * 528];       // cross-wave reduce             16.9 KB
  __shared__ float xpre[3][256];       // x-projections for current step
  __shared__ float sZ[256];            // z gate
  __shared__ float sBias[32];          // b_r[8] b_z[8] b_h[8] b_out[4]

  const int tid = threadIdx.x;
  const int bid = blockIdx.x;
  const int jt = bid & 127, bhalf = bid >> 7;
  const int j0 = jt * 8, o0 = jt * 4, bbase = bhalf * 32;

  // ---- prologue: weight slices -> swizzled LDS ----
  #pragma unroll
  for (int kk2 = 0; kk2 < 2; ++kk2){
    const int k = tid * 2 + kk2;           // 0..1023
    f4 vr  = ld4(W_rh + (size_t)k * HH + j0);
    f4 vr2 = ld4(W_rh + (size_t)k * HH + j0 + 4);
    f4 vz  = ld4(W_zh + (size_t)k * HH + j0);
    f4 vz2 = ld4(W_zh + (size_t)k * HH + j0 + 4);
    f4 vh  = ld4(W_hh + (size_t)k * HH + j0);
    f4 vh2 = ld4(W_hh + (size_t)k * HH + j0 + 4);
    const int kx = swz(k);
    float ar[8] = {vr.x,vr.y,vr.z,vr.w,vr2.x,vr2.y,vr2.z,vr2.w};
    float az[8] = {vz.x,vz.y,vz.z,vz.w,vz2.x,vz2.y,vz2.z,vz2.w};
    float ah[8] = {vh.x,vh.y,vh.z,vh.w,vh2.x,vh2.y,vh2.z,vh2.w};
    #pragma unroll
    for (int c = 0; c < 8; ++c){
      sW[0*8192 + c*1024 + kx] = ar[c];
      sW[1*8192 + c*1024 + kx] = az[c];
      sW[2*8192 + c*1024 + kx] = ah[c];
    }
  }
  if (tid < 8){
    sBias[tid]      = b_r[j0 + tid];
    sBias[8 + tid]  = b_z[j0 + tid];
    sBias[16 + tid] = b_h[j0 + tid];
    if (tid < 4) sBias[24 + tid] = b_out[o0 + tid];
  }

  const int bg = tid & 7, b0 = bbase + bg * 4;
  const int ksec = tid >> 3;           // 0..63
  const int wv = tid >> 6;             // wave 0..7
  const bool wr0 = ((tid & 56) == 0);
  const int kh0 = ksec * 16;           // K=1024 / 64
  const int kx0 = ksec * 8;            // K=512  / 64
  __syncthreads();

  for (int t = -1; t < TT; ++t){
    f4 st4[16];                        // h stash, A -> A2
    if (t >= 0){
      // ================= A: r gate =================
      float aR[8][4] = {};
      ldc16(h + kh0 * BB + b0, st4);   // coherent h read (all 16 k at once)
      #pragma unroll
      for (int i4 = 0; i4 < 4; ++i4){
        const int kxc = swz(kh0 + i4*4);
        #pragma unroll
        for (int c = 0; c < 8; ++c){
          f4 wf = *reinterpret_cast<const f4*>(&sW[0*8192 + c*1024 + kxc]);
          float wvv[4] = {wf.x, wf.y, wf.z, wf.w};
          #pragma unroll
          for (int kk = 0; kk < 4; ++kk){
            const f4 hv = st4[i4*4+kk];
            aR[c][0] = fmaf(wvv[kk], hv.x, aR[c][0]);
            aR[c][1] = fmaf(wvv[kk], hv.y, aR[c][1]);
            aR[c][2] = fmaf(wvv[kk], hv.z, aR[c][2]);
            aR[c][3] = fmaf(wvv[kk], hv.w, aR[c][3]);
          }
        }
      }
      #pragma unroll
      for (int c = 0; c < 8; ++c)
        #pragma unroll
        for (int bb = 0; bb < 4; ++bb) WREDUCE(aR[c][bb]);
      if (wr0)
        #pragma unroll
        for (int c = 0; c < 8; ++c)
          #pragma unroll
          for (int bb = 0; bb < 4; ++bb)
            red[wv*528 + c*32 + bg*4 + bb] = aR[c][bb];
      __syncthreads();
      if (tid < 256){
        float sum = 0.f;
        #pragma unroll
        for (int w = 0; w < 8; ++w) sum += red[w*528 + tid];
        const int c = tid >> 5, bl = tid & 31;
        const float v = sum + xpre[0][tid] + sBias[c];
        const float rr = 1.f / (1.f + expf(-v));
        const int jg = j0 + c, bgl = bbase + bl;
        stc1(&s[jg*BB + bgl], rr * ldc1(&h[jg*BB + bgl]));
      }
      __syncthreads();                 // per-wave vmcnt(0) drains sc1 stores
      if (tid == 0) g_arrive(bars, bhalf, jt, 2*t + 1);

      // ========== A2: z gate + y_{t-1} (hides barrier A) ==========
      float aZ[8][4] = {};
      float aY[4][4] = {};
      #pragma unroll
      for (int i4 = 0; i4 < 4; ++i4){
        const int kc = kh0 + i4*4;
        const int kxc = swz(kc);
        #pragma unroll
        for (int c = 0; c < 8; ++c){
          f4 wf = *reinterpret_cast<const f4*>(&sW[1*8192 + c*1024 + kxc]);
          float wvv[4] = {wf.x, wf.y, wf.z, wf.w};
          #pragma unroll
          for (int kk = 0; kk < 4; ++kk){
            const f4 hv = st4[i4*4+kk];
            aZ[c][0] = fmaf(wvv[kk], hv.x, aZ[c][0]);
            aZ[c][1] = fmaf(wvv[kk], hv.y, aZ[c][1]);
            aZ[c][2] = fmaf(wvv[kk], hv.z, aZ[c][2]);
            aZ[c][3] = fmaf(wvv[kk], hv.w, aZ[c][3]);
          }
        }
        #pragma unroll
        for (int oc = 0; oc < 4; ++oc){
          f4 wo = ld4(W_out + (size_t)(o0 + oc) * HH + kc);   // L2-hot now
          float wvv[4] = {wo.x, wo.y, wo.z, wo.w};
          #pragma unroll
          for (int kk = 0; kk < 4; ++kk){
            const f4 hv = st4[i4*4+kk];
            aY[oc][0] = fmaf(wvv[kk], hv.x, aY[oc][0]);
            aY[oc][1] = fmaf(wvv[kk], hv.y, aY[oc][1]);
            aY[oc][2] = fmaf(wvv[kk], hv.z, aY[oc][2]);
            aY[oc][3] = fmaf(wvv[kk], hv.w, aY[oc][3]);
          }
        }
      }
      #pragma unroll
      for (int c = 0; c < 8; ++c)
        #pragma unroll
        for (int bb = 0; bb < 4; ++bb) WREDUCE(aZ[c][bb]);
      #pragma unroll
      for (int oc = 0; oc < 4; ++oc)
        #pragma unroll
        for (int bb = 0; bb < 4; ++bb) WREDUCE(aY[oc][bb]);
      if (wr0){
        #pragma unroll
        for (int c = 0; c < 8; ++c)
          #pragma unroll
          for (int bb = 0; bb < 4; ++bb)
            red[wv*528 + c*32 + bg*4 + bb] = aZ[c][bb];
        #pragma unroll
        for (int oc = 0; oc < 4; ++oc)
          #pragma unroll
          for (int bb = 0; bb < 4; ++bb)
            red[wv*528 + 256 + oc*32 + bg*4 + bb] = aY[oc][bb];
      }
      __syncthreads();
      if (tid < 256){
        float sum = 0.f;
        #pragma unroll
        for (int w = 0; w < 8; ++w) sum += red[w*528 + tid];
        const int c = tid >> 5;
        sZ[tid] = 1.f / (1.f + expf(-(sum + xpre[1][tid] + sBias[8 + c])));
      } else if (tid < 384){
        const int idx = tid - 256;
        float sum = 0.f;
        #pragma unroll
        for (int w = 0; w < 8; ++w) sum += red[w*528 + tid];
        const int oc = idx >> 5, bl = idx & 31;
        if (t > 0)
          out[((size_t)(t-1)*BB + bbase + bl)*OO + o0 + oc] = sum + sBias[24 + oc];
      }
      if (tid == 0) g_wait(bars, bhalf, 2*t + 1);
      __syncthreads();

      // ================= B: candidate + h update =================
      float aH[8][4] = {};
      f4 sv16[16];
      ldc16(s + kh0 * BB + b0, sv16);  // coherent s read
      #pragma unroll
      for (int i4 = 0; i4 < 4; ++i4){
        const int kxc = swz(kh0 + i4*4);
        #pragma unroll
        for (int c = 0; c < 8; ++c){
          f4 wf = *reinterpret_cast<const f4*>(&sW[2*8192 + c*1024 + kxc]);
          float wvv[4] = {wf.x, wf.y, wf.z, wf.w};
          #pragma unroll
          for (int kk = 0; kk < 4; ++kk){
            const f4 sv = sv16[i4*4+kk];
            aH[c][0] = fmaf(wvv[kk], sv.x, aH[c][0]);
            aH[c][1] = fmaf(wvv[kk], sv.y, aH[c][1]);
            aH[c][2] = fmaf(wvv[kk], sv.z, aH[c][2]);
            aH[c][3] = fmaf(wvv[kk], sv.w, aH[c][3]);
          }
        }
      }
      #pragma unroll
      for (int c = 0; c < 8; ++c)
        #pragma unroll
        for (int bb = 0; bb < 4; ++bb) WREDUCE(aH[c][bb]);
      if (wr0)
        #pragma unroll
        for (int c = 0; c < 8; ++c)
          #pragma unroll
          for (int bb = 0; bb < 4; ++bb)
            red[wv*528 + c*32 + bg*4 + bb] = aH[c][bb];
      __syncthreads();
      if (tid < 256){
        float sum = 0.f;
        #pragma unroll
        for (int w = 0; w < 8; ++w) sum += red[w*528 + tid];
        const int c = tid >> 5, bl = tid & 31;
        const int jg = j0 + c, bgl = bbase + bl;
        const float ht = tanhf(sum + xpre[2][tid] + sBias[16 + c]);
        const float z = sZ[tid];
        const float hold = ldc1(&h[jg*BB + bgl]);
        const float hnew = fmaf(z, ht - hold, hold);
        stc1(&h[jg*BB + bgl], hnew);
        if (t == TT - 1) out[(size_t)TT*BB*OO + (size_t)bgl*HH + jg] = hnew;
      }
      __syncthreads();                 // drains sc1 h stores per-wave
      if (tid == 0) g_arrive(bars, bhalf, jt, 2*t + 2);
    }

    // ============ C: x-projections for step t+1 (hides barrier B) ============
    if (t + 1 < TT){
      const int tc = t + 1;
      float aXr[8][4] = {}, aXz[8][4] = {}, aXh[8][4] = {};
      const float* xb = xT + (size_t)tc * II * BB + kx0 * BB + b0;
      #pragma unroll
      for (int i4 = 0; i4 < 2; ++i4){
        f4 xv4[4];
        #pragma unroll
        for (int kk = 0; kk < 4; ++kk) xv4[kk] = ld4(xb + (i4*4+kk) * BB);
        #pragma unroll
        for (int c = 0; c < 8; ++c){
          f4 wr_ = ld4(WxTr + (size_t)(j0 + c) * II + kx0 + i4*4);
          f4 wz_ = ld4(WxTz + (size_t)(j0 + c) * II + kx0 + i4*4);
          f4 wh_ = ld4(WxTh + (size_t)(j0 + c) * II + kx0 + i4*4);
          float wrv[4] = {wr_.x, wr_.y, wr_.z, wr_.w};
          float wzv[4] = {wz_.x, wz_.y, wz_.z, wz_.w};
          float whv[4] = {wh_.x, wh_.y, wh_.z, wh_.w};
          #pragma unroll
          for (int kk = 0; kk < 4; ++kk){
            const f4 xv = xv4[kk];
            aXr[c][0] = fmaf(wrv[kk], xv.x, aXr[c][0]);
            aXr[c][1] = fmaf(wrv[kk], xv.y, aXr[c][1]);
            aXr[c][2] = fmaf(wrv[kk], xv.z, aXr[c][2]);
            aXr[c][3] = fmaf(wrv[kk], xv.w, aXr[c][3]);
            aXz[c][0] = fmaf(wzv[kk], xv.x, aXz[c][0]);
            aXz[c][1] = fmaf(wzv[kk], xv.y, aXz[c][1]);
            aXz[c][2] = fmaf(wzv[kk], xv.z, aXz[c][2]);
            aXz[c][3] = fmaf(wzv[kk], xv.w, aXz[c][3]);
            aXh[c][0] = fmaf(whv[kk], xv.x, aXh[c][0]);
            aXh[c][1] = fmaf(whv[kk], xv.y, aXh[c][1]);
            aXh[c][2] = fmaf(whv[kk], xv.z, aXh[c][2]);
            aXh[c][3] = fmaf(whv[kk], xv.w, aXh[c][3]);
          }
        }
      }
      #pragma unroll
      for (int c = 0; c < 8; ++c)
        #pragma unroll
        for (int bb = 0; bb < 4; ++bb){ WREDUCE(aXr[c][bb]); WREDUCE(aXz[c][bb]); WREDUCE(aXh[c][bb]); }
      if (wr0)
        #pragma unroll
        for (int c = 0; c < 8; ++c)
          #pragma unroll
          for (int bb = 0; bb < 4; ++bb){
            red[wv*528 + c*32 + bg*4 + bb]       = aXr[c][bb];
            red[wv*528 + 256 + c*32 + bg*4 + bb] = aXz[c][bb];
          }
      __syncthreads();
      {
        float sum = 0.f;
        #pragma unroll
        for (int w = 0; w < 8; ++w) sum += red[w*528 + tid];
        if (tid < 256) xpre[0][tid] = sum;
        else           xpre[1][tid - 256] = sum;
      }
      __syncthreads();
      if (wr0)
        #pragma unroll
        for (int c = 0; c < 8; ++c)
          #pragma unroll
          for (int bb = 0; bb < 4; ++bb)
            red[wv*528 + c*32 + bg*4 + bb] = aXh[c][bb];
      __syncthreads();
      if (tid < 256){
        float sum = 0.f;
        #pragma unroll
        for (int w = 0; w < 8; ++w) sum += red[w*528 + tid];
        xpre[2][tid] = sum;
      }
      __syncthreads();
    }

    if (t >= 0){
      if (tid == 0) g_wait(bars, bhalf, 2*t + 2);
      __syncthreads();
    }
  }

  // ================= trailing y_{T-1} from final h =================
  {
    float aY[4][4] = {};
    f4 hv16[16];
    ldc16(h + kh0 * BB + b0, hv16);
    #pragma unroll
    for (int i4 = 0; i4 < 4; ++i4){
      const int kc = kh0 + i4*4;
      #pragma unroll
      for (int oc = 0; oc < 4; ++oc){
        f4 wo = ld4(W_out + (size_t)(o0 + oc) * HH + kc);
        float wvv[4] = {wo.x, wo.y, wo.z, wo.w};
        #pragma unroll
        for (int kk = 0; kk < 4; ++kk){
          const f4 hv = hv16[i4*4+kk];
          aY[oc][0] = fmaf(wvv[kk], hv.x, aY[oc][0]);
          aY[oc][1] = fmaf(wvv[kk], hv.y, aY[oc][1]);
          aY[oc][2] = fmaf(wvv[kk], hv.z, aY[oc][2]);
          aY[oc][3] = fmaf(wvv[kk], hv.w, aY[oc][3]);
        }
      }
    }
    #pragma unroll
    for (int oc = 0; oc < 4; ++oc)
      #pragma unroll
      for (int bb = 0; bb < 4; ++bb) WREDUCE(aY[oc][bb]);
    if (wr0)
      #pragma unroll
      for (int oc = 0; oc < 4; ++oc)
        #pragma unroll
        for (int bb = 0; bb < 4; ++bb)
          red[wv*528 + oc*32 + bg*4 + bb] = aY[oc][bb];
    __syncthreads();
    if (tid < 128){
      float sum = 0.f;
      #pragma unroll
      for (int w = 0; w < 8; ++w) sum += red[w*528 + tid];
      const int oc = tid >> 5, bl = tid & 31;
      out[((size_t)(TT-1)*BB + bbase + bl)*OO + o0 + oc] = sum + sBias[24 + oc];
    }
  }
}

// ---------------- host ----------------
extern "C" void kernel_launch(void* const* d_in, const int* in_sizes, int n_in,
                              void* d_out, int out_size, void* d_ws, size_t ws_size,
                              hipStream_t stream) {
  const float* x     = (const float*)d_in[0];
  const float* st    = (const float*)d_in[1];
  const float* W_zh  = (const float*)d_in[2];
  const float* W_zx  = (const float*)d_in[3];
  const float* b_z   = (const float*)d_in[4];
  const float* W_rh  = (const float*)d_in[5];
  const float* W_rx  = (const float*)d_in[6];
  const float* b_r   = (const float*)d_in[7];
  const float* W_hh  = (const float*)d_in[8];
  const float* W_hx  = (const float*)d_in[9];
  const float* b_h   = (const float*)d_in[10];
  const float* W_out = (const float*)d_in[11];
  const float* b_out = (const float*)d_in[12];
  float* out = (float*)d_out;
  float* ws  = (float*)d_ws;

  const size_t xT_sz = (size_t)TT * II * BB;   // 16,777,216
  const size_t wx_sz = (size_t)II * HH;        //    524,288
  const size_t h_sz  = (size_t)HH * BB;        //     65,536
  const size_t need  = (xT_sz + 3*wx_sz + 2*h_sz) * sizeof(float) + 512*sizeof(unsigned);
  if (ws_size < need) return;

  float* xT   = ws;
  float* WxTr = xT + xT_sz;
  float* WxTz = WxTr + wx_sz;
  float* WxTh = WxTz + wx_sz;
  float* h    = WxTh + wx_sz;
  float* s    = h + h_sz;
  unsigned* bars = (unsigned*)(s + h_sz);

  k_transpose_x <<<8192, 256, 0, stream>>>(x, xT);
  k_transpose_wx<<<2048, 256, 0, stream>>>(W_rx, WxTr);
  k_transpose_wx<<<2048, 256, 0, stream>>>(W_zx, WxTz);
  k_transpose_wx<<<2048, 256, 0, stream>>>(W_hx, WxTh);
  k_transpose_h0<<< 256, 256, 0, stream>>>(st, h);
  k_init_bars   <<<   1, 512, 0, stream>>>(bars);

  k_gru<<<256, NTHR, 0, stream>>>(xT, WxTr, WxTz, WxTh, h, s,
                                  W_zh, b_z, W_rh, b_r, W_hh, b_h,
                                  W_out, b_out, out, bars);
}